// Round 15
// baseline (484.228 us; speedup 1.0000x reference)
//
#include <hip/hip_runtime.h>
#include <math.h>

#define NXR 8192
#define NCR 8192
#define HD  512
#define NSL 8            // attention j-slices (R11-proven)
#define JC  (NCR / NSL)  // 1024 cols per attention block
#define KSTR 520         // padded LDS col stride (elems)

typedef short s16x8 __attribute__((ext_vector_type(8)));
typedef float f32x4 __attribute__((ext_vector_type(4)));
typedef unsigned short u16;

struct P11 { const float* p[11]; };
struct P3  { const float* p[3]; };
struct MB12 { const float* p[12]; };  // 0..8: bh[l*3+net]; 9: Qbo; 10: Kbo; 11: Vbo

__device__ inline u16 f2bf(float f) {
    unsigned int u = __float_as_uint(f);
    u = (u + 0x7FFFu + ((u >> 16) & 1u)) >> 16;
    return (u16)u;
}
__device__ inline float bf2f(u16 h) {
    return __uint_as_float(((unsigned int)h) << 16);
}

// ---------------------------------------------------------------------------
// Fused weight transpose + bf16 convert: out[z][n][k] = (bf16)in_z[k][n].
// Slots: z = l*3+net (hidden), 9 = QWo, 10 = KWo. grid (16,16,11).
// ---------------------------------------------------------------------------
__global__ __launch_bounds__(256) void transpose_w_all(
    P11 srcs, u16* __restrict__ out)
{
    const float* in = srcs.p[blockIdx.z];
    u16* o = out + (size_t)blockIdx.z * HD * HD;
    __shared__ float tile[32][33];
    int bx = blockIdx.x * 32, by = blockIdx.y * 32;
    int tx = threadIdx.x & 31, ty = threadIdx.x >> 5;
    for (int r = ty; r < 32; r += 8)
        tile[r][tx] = in[(size_t)(by + r) * HD + bx + tx];
    __syncthreads();
    for (int r = ty; r < 32; r += 8)
        o[(size_t)(bx + r) * HD + by + tx] = f2bf(tile[tx][r]);
}

// ---------------------------------------------------------------------------
// Layer 0, 8 outputs/thread, bf16x8 store. grid (NXR*HD/2048, 1, 3)
// ---------------------------------------------------------------------------
__global__ __launch_bounds__(256) void layer0_all(
    const float* __restrict__ x, const float* __restrict__ c,
    P3 W0p, P3 b0p, u16* __restrict__ H)
{
    int z = blockIdx.z;
    const float* X  = (z == 0) ? x : c;
    const float* W0 = W0p.p[z];
    const float* b0 = b0p.p[z];
    u16* Hn = H + (size_t)z * NXR * HD;

    int idx = (blockIdx.x * 256 + threadIdx.x) * 8;
    int n = idx & (HD - 1);
    int row = idx >> 9;
    float x0 = X[row * 3 + 0], x1 = X[row * 3 + 1], x2 = X[row * 3 + 2];
    s16x8 o;
#pragma unroll
    for (int j = 0; j < 8; ++j) {
        float v = x0 * W0[n + j] + x1 * W0[HD + n + j] + x2 * W0[2 * HD + n + j] + b0[n + j];
        ((u16*)&o)[j] = f2bf(__sinf(v));
    }
    *(s16x8*)&Hn[idx] = o;
}

// ---------------------------------------------------------------------------
// MLP MEGA-KERNEL: all hidden layers + output layer in ONE dispatch.
// Row-band parallel: block = 128 rows of net z; layers have no cross-block
// dependency, so the whole 4-layer chain runs in-kernel, IN-PLACE on the
// block's strip (qf is fully register-resident before any store of a layer;
// __threadfence() orders stores->reload across layers).
// Per layer: load qf (32 rows/wave, all K) -> 16 col-tiles of the proven
// gemm_rs tile (stage W 32x512 in LDS; kt-loop 2 ds_read_b128 + 4 MFMA).
// Q/K nets: 3 hidden (sin) + output (linear). V net: 3 hidden + in-register
// vout reduction (VWo staged in LDS, 4-lane shuffle reduce) -> Vf fp32.
// grid (64, 1, 3) = 192 blocks.
// ---------------------------------------------------------------------------
__global__ __launch_bounds__(256) void mlp_mega(
    u16* __restrict__ h, const u16* __restrict__ wT,
    MB12 mb, const float* __restrict__ VWo, float* __restrict__ Vf)
{
    __shared__ u16 Ws[32 * KSTR];      // 33,280 B
    __shared__ float VWs[HD * 3];      // 6,144 B (V-net only)

    const size_t WTN = (size_t)HD * HD;
    const int net = blockIdx.z;
    const int tid = threadIdx.x;
    const int wave = tid >> 6, lane = tid & 63;
    const int row0 = blockIdx.x * 128;
    u16* strip = h + (size_t)net * NXR * HD;

    const int qm = lane & 15;
    const int g  = lane >> 4;

    const int nlayers = (net == 2) ? 3 : 4;

    s16x8 qf[16][2];

    for (int layer = 0; layer < nlayers; ++layer) {
        const u16* Wt = (layer < 3) ? wT + (size_t)(layer * 3 + net) * WTN
                                    : wT + (size_t)(9 + net) * WTN;
        const float* bias_p = mb.p[(layer < 3) ? layer * 3 + net : 9 + net];
        const int act = (layer < 3);

        // ---- load this wave's 32 rows, all K, into registers ----
        {
            const u16* ap = strip + (size_t)(row0 + wave * 32 + qm) * HD + g * 8;
#pragma unroll
            for (int t = 0; t < 16; ++t) {
                qf[t][0] = *(const s16x8*)(ap + t * 32);
                qf[t][1] = *(const s16x8*)(ap + (size_t)16 * HD + t * 32);
            }
        }

        for (int ct = 0; ct < 16; ++ct) {
            const int col0 = ct * 32;

            // stage W tile [32 cols][512] into LDS
#pragma unroll
            for (int i = 0; i < 8; ++i) {
                int chunk = i * 256 + tid;
                int cc = chunk >> 6, ch = chunk & 63;
                s16x8 v = *(const s16x8*)(Wt + (size_t)(col0 + cc) * HD + ch * 8);
                *(s16x8*)&Ws[cc * KSTR + ch * 8] = v;
            }
            __syncthreads();

            f32x4 acc[2][2] = {};
#pragma unroll
            for (int kt = 0; kt < 16; ++kt) {
                s16x8 b0 = *(const s16x8*)&Ws[qm * KSTR + kt * 32 + g * 8];
                s16x8 b1 = *(const s16x8*)&Ws[(16 + qm) * KSTR + kt * 32 + g * 8];
                acc[0][0] = __builtin_amdgcn_mfma_f32_16x16x32_bf16(qf[kt][0], b0, acc[0][0], 0, 0, 0);
                acc[0][1] = __builtin_amdgcn_mfma_f32_16x16x32_bf16(qf[kt][0], b1, acc[0][1], 0, 0, 0);
                acc[1][0] = __builtin_amdgcn_mfma_f32_16x16x32_bf16(qf[kt][1], b0, acc[1][0], 0, 0, 0);
                acc[1][1] = __builtin_amdgcn_mfma_f32_16x16x32_bf16(qf[kt][1], b1, acc[1][1], 0, 0, 0);
            }

            float bv0 = bias_p[col0 + qm];
            float bv1 = bias_p[col0 + 16 + qm];
#pragma unroll
            for (int hh = 0; hh < 2; ++hh) {
#pragma unroll
                for (int r = 0; r < 4; ++r) {
                    int grow = row0 + wave * 32 + hh * 16 + g * 4 + r;
                    float v0 = acc[hh][0][r] + bv0;
                    float v1 = acc[hh][1][r] + bv1;
                    if (act) { v0 = __sinf(v0); v1 = __sinf(v1); }
                    strip[(size_t)grow * HD + col0 + qm]      = f2bf(v0);
                    strip[(size_t)grow * HD + col0 + 16 + qm] = f2bf(v1);
                }
            }
            __syncthreads();   // Ws reused next col-tile
        }
        __threadfence();       // drain stores + L1 inval before next qf reload
    }

    // ---- V net: vout from registers (strip now holds h3) ----
    if (net == 2) {
        {
            const u16* ap = strip + (size_t)(row0 + wave * 32 + qm) * HD + g * 8;
#pragma unroll
            for (int t = 0; t < 16; ++t) {
                qf[t][0] = *(const s16x8*)(ap + t * 32);
                qf[t][1] = *(const s16x8*)(ap + (size_t)16 * HD + t * 32);
            }
        }
        for (int i = tid; i < HD * 3; i += 256) VWs[i] = VWo[i];
        __syncthreads();
        const float* Vbo = mb.p[11];

        float o[2][3] = {};
#pragma unroll
        for (int t = 0; t < 16; ++t)
#pragma unroll
            for (int hh = 0; hh < 2; ++hh)
#pragma unroll
                for (int j = 0; j < 8; ++j) {
                    float a = bf2f(((const u16*)&qf[t][hh])[j]);
                    int k = t * 32 + g * 8 + j;
                    o[hh][0] += a * VWs[k * 3 + 0];
                    o[hh][1] += a * VWs[k * 3 + 1];
                    o[hh][2] += a * VWs[k * 3 + 2];
                }
        // reduce over the 4 g-lanes (lane = g*16 + qm)
#pragma unroll
        for (int hh = 0; hh < 2; ++hh)
#pragma unroll
            for (int cc = 0; cc < 3; ++cc) {
                float v = o[hh][cc];
                v += __shfl_down(v, 32);
                v += __shfl_down(v, 16);
                if (g == 0)
                    Vf[(size_t)(row0 + wave * 32 + hh * 16 + qm) * 3 + cc] = v + Vbo[cc];
            }
    }
}

// ---------------------------------------------------------------------------
// Fused attention (R11-exact): Q-in-registers (32 rows/wave), K-in-LDS.
// Block = 128 Q-rows x JC=1024 cols; grid (NSL=8, 64) = 512 blocks.
// ---------------------------------------------------------------------------
__global__ __launch_bounds__(256) void attn_mfma(
    const u16* __restrict__ Q, const u16* __restrict__ K,
    const float* __restrict__ V, float* __restrict__ out)
{
    __shared__ u16 Ks[32 * KSTR];   // 33,280 B

    const int tid = threadIdx.x;
    const int wave = tid >> 6, lane = tid & 63;
    const int row0 = blockIdx.y * 128;
    const int col_base = blockIdx.x * JC;

    const int qm = lane & 15;
    const int g  = lane >> 4;

    s16x8 qf[16][2];
    {
        const u16* qp = Q + (size_t)(row0 + wave * 32 + qm) * HD + g * 8;
#pragma unroll
        for (int t = 0; t < 16; ++t) {
            qf[t][0] = *(const s16x8*)(qp + t * 32);
            qf[t][1] = *(const s16x8*)(qp + (size_t)16 * HD + t * 32);
        }
    }

    float po[2][4][3] = {};

    for (int jt = 0; jt < JC / 32; ++jt) {
        const int col0 = col_base + jt * 32;

#pragma unroll
        for (int i = 0; i < 8; ++i) {
            int chunk = i * 256 + tid;
            int cc = chunk >> 6;
            int ch = chunk & 63;
            s16x8 v = *(const s16x8*)(K + (size_t)(col0 + cc) * HD + ch * 8);
            *(s16x8*)&Ks[cc * KSTR + ch * 8] = v;
        }
        __syncthreads();

        float vv[2][3];
#pragma unroll
        for (int ct = 0; ct < 2; ++ct) {
            size_t vr = (size_t)(col0 + ct * 16 + qm) * 3;
            vv[ct][0] = V[vr + 0];
            vv[ct][1] = V[vr + 1];
            vv[ct][2] = V[vr + 2];
        }

        f32x4 acc[2][2] = {};
#pragma unroll
        for (int kt = 0; kt < 16; ++kt) {
            s16x8 b0 = *(const s16x8*)&Ks[qm * KSTR + kt * 32 + g * 8];
            s16x8 b1 = *(const s16x8*)&Ks[(16 + qm) * KSTR + kt * 32 + g * 8];
            acc[0][0] = __builtin_amdgcn_mfma_f32_16x16x32_bf16(qf[kt][0], b0, acc[0][0], 0, 0, 0);
            acc[0][1] = __builtin_amdgcn_mfma_f32_16x16x32_bf16(qf[kt][0], b1, acc[0][1], 0, 0, 0);
            acc[1][0] = __builtin_amdgcn_mfma_f32_16x16x32_bf16(qf[kt][1], b0, acc[1][0], 0, 0, 0);
            acc[1][1] = __builtin_amdgcn_mfma_f32_16x16x32_bf16(qf[kt][1], b1, acc[1][1], 0, 0, 0);
        }

#pragma unroll
        for (int h = 0; h < 2; ++h)
#pragma unroll
            for (int ct = 0; ct < 2; ++ct)
#pragma unroll
                for (int r = 0; r < 4; ++r) {
                    float s = __builtin_amdgcn_rcpf(1.f + __expf(-acc[h][ct][r]));
                    po[h][r][0] += s * vv[ct][0];
                    po[h][r][1] += s * vv[ct][1];
                    po[h][r][2] += s * vv[ct][2];
                }
        __syncthreads();
    }

#pragma unroll
    for (int h = 0; h < 2; ++h)
#pragma unroll
        for (int r = 0; r < 4; ++r)
#pragma unroll
            for (int c = 0; c < 3; ++c) {
                float v = po[h][r][c];
                v += __shfl_down(v, 8, 16);
                v += __shfl_down(v, 4, 16);
                v += __shfl_down(v, 2, 16);
                v += __shfl_down(v, 1, 16);
                if (qm == 0)
                    atomicAdd(&out[(size_t)(row0 + wave * 32 + h * 16 + g * 4 + r) * 3 + c], v);
            }
}

// ---------------------------------------------------------------------------
// Workspace (single path, 29.6 MB — under the R5-proven 38.1 MB):
//   wT [0, 5.50 MB) | hA [5.50, 29.50 MB) (3 net strips, in-place MLP)
//   | Vf [29.50, 29.60 MB)
// ---------------------------------------------------------------------------
extern "C" void kernel_launch(void* const* d_in, const int* in_sizes, int n_in,
                              void* d_out, int out_size, void* d_ws, size_t ws_size,
                              hipStream_t stream)
{
    const float* x   = (const float*)d_in[0];
    const float* c   = (const float*)d_in[1];
    const float* QW0 = (const float*)d_in[2];
    const float* Qb0 = (const float*)d_in[3];
    const float* QWh = (const float*)d_in[4];
    const float* Qbh = (const float*)d_in[5];
    const float* QWo = (const float*)d_in[6];
    const float* Qbo = (const float*)d_in[7];
    const float* KW0 = (const float*)d_in[8];
    const float* Kb0 = (const float*)d_in[9];
    const float* KWh = (const float*)d_in[10];
    const float* Kbh = (const float*)d_in[11];
    const float* KWo = (const float*)d_in[12];
    const float* Kbo = (const float*)d_in[13];
    const float* VW0 = (const float*)d_in[14];
    const float* Vb0 = (const float*)d_in[15];
    const float* VWh = (const float*)d_in[16];
    const float* Vbh = (const float*)d_in[17];
    const float* VWo = (const float*)d_in[18];
    const float* Vbo = (const float*)d_in[19];

    char* ws = (char*)d_ws;
    const size_t WTN = (size_t)HD * HD;
    const size_t NET = (size_t)NXR * HD;

    u16*   wT = (u16*)ws;                                   // 5.5 MB
    u16*   hA = (u16*)(ws + 11 * WTN * sizeof(u16));        // 24 MB (3 strips)
    float* Vf = (float*)(ws + 11 * WTN * sizeof(u16) + 3 * NET * sizeof(u16));

    // ---- weight transposes (1 dispatch) ----
    P11 tsrc;
    for (int l = 0; l < 3; ++l) {
        tsrc.p[l * 3 + 0] = QWh + (size_t)l * WTN;
        tsrc.p[l * 3 + 1] = KWh + (size_t)l * WTN;
        tsrc.p[l * 3 + 2] = VWh + (size_t)l * WTN;
    }
    tsrc.p[9]  = QWo;
    tsrc.p[10] = KWo;
    transpose_w_all<<<dim3(16, 16, 11), 256, 0, stream>>>(tsrc, wT);

    // ---- layer 0 (1 dispatch, 3 nets) ----
    {
        P3 w0 = {{QW0, KW0, VW0}}, b0 = {{Qb0, Kb0, Vb0}};
        layer0_all<<<dim3(NXR * HD / 2048, 1, 3), 256, 0, stream>>>(x, c, w0, b0, hA);
    }

    // ---- MLP mega-kernel (1 dispatch: 3 hidden + output + vout) ----
    {
        MB12 mb;
        for (int l = 0; l < 3; ++l) {
            mb.p[l * 3 + 0] = Qbh + (size_t)l * HD;
            mb.p[l * 3 + 1] = Kbh + (size_t)l * HD;
            mb.p[l * 3 + 2] = Vbh + (size_t)l * HD;
        }
        mb.p[9]  = Qbo;
        mb.p[10] = Kbo;
        mb.p[11] = Vbo;
        mlp_mega<<<dim3(NXR / 128, 1, 3), 256, 0, stream>>>(hA, wT, mb, VWo, Vf);
    }

    // ---- attention ----
    hipMemsetAsync(d_out, 0, (size_t)out_size * sizeof(float), stream);
    attn_mfma<<<dim3(NSL, NXR / 128), 256, 0, stream>>>(
        hA, hA + NET, Vf, (float*)d_out);
}